// Round 8
// baseline (220.404 us; speedup 1.0000x reference)
//
#include <hip/hip_runtime.h>
#include <math.h>

#define N 512
#define PLANE ((size_t)N * N)
#define NEG2PI (-6.28318530717958647692f)

// ---------------------------------------------------------------------------
// In-register 8-point complex DFT (DIF), w8 = e^{-2pi i/8}  [validated R1-R6]
// ---------------------------------------------------------------------------
__device__ inline void dft8(float (&xr)[8], float (&xi)[8]) {
    const float S = 0.70710678118654752440f;
    float t0r = xr[0] + xr[4], t0i = xi[0] + xi[4];
    float t4r = xr[0] - xr[4], t4i = xi[0] - xi[4];
    float t1r = xr[1] + xr[5], t1i = xi[1] + xi[5];
    float t5r = xr[1] - xr[5], t5i = xi[1] - xi[5];
    float t2r = xr[2] + xr[6], t2i = xi[2] + xi[6];
    float t6r = xr[2] - xr[6], t6i = xi[2] - xi[6];
    float t3r = xr[3] + xr[7], t3i = xi[3] + xi[7];
    float t7r = xr[3] - xr[7], t7i = xi[3] - xi[7];
    float o1r = S * (t5r + t5i), o1i = S * (t5i - t5r);
    float o2r = t6i,             o2i = -t6r;
    float o3r = S * (t7i - t7r), o3i = -S * (t7r + t7i);
    float p0r = t0r + t2r, p0i = t0i + t2i;
    float p1r = t1r + t3r, p1i = t1i + t3i;
    float q0r = t0r - t2r, q0i = t0i - t2i;
    float q1r = t1i - t3i, q1i = -(t1r - t3r);
    xr[0] = p0r + p1r; xi[0] = p0i + p1i;
    xr[4] = p0r - p1r; xi[4] = p0i - p1i;
    xr[2] = q0r + q1r; xi[2] = q0i + q1i;
    xr[6] = q0r - q1r; xi[6] = q0i - q1i;
    float r0r = t4r + o2r, r0i = t4i + o2i;
    float r1r = o1r + o3r, r1i = o1i + o3i;
    float u0r = t4r - o2r, u0i = t4i - o2i;
    float u1r = o1i - o3i, u1i = -(o1r - o3r);
    xr[1] = r0r + r1r; xi[1] = r0i + r1i;
    xr[5] = r0r - r1r; xi[5] = r0i - r1i;
    xr[3] = u0r + u1r; xi[3] = u0i + u1i;
    xr[7] = u0r - u1r; xi[7] = u0i - u1i;
}

__device__ inline void twiddle_apply(float (&xr)[8], float (&xi)[8], float ang1) {
    float ts = __sinf(ang1), tc = __cosf(ang1);
    float wr = tc, wi = ts;
    #pragma unroll
    for (int k = 1; k < 8; ++k) {
        float nr = xr[k] * wr - xi[k] * wi;
        float ni = xr[k] * wi + xi[k] * wr;
        xr[k] = nr; xi[k] = ni;
        float w2r = wr * tc - wi * ts;
        float w2i = wr * ts + wi * tc;
        wr = w2r; wi = w2i;
    }
}

// ---------------------------------------------------------------------------
// Per-wave 512-pt FFT, radix-8 DIF. Input xr/xi[q] = x[lane + 64q].
// Output xr/xi[k] = X[64k + 8*(lane&7) + (lane>>3)] (digit-reversed).
// LDS scratch 576 floats/wave, phys(i) = i + i/8. Wave-synchronous.
// ---------------------------------------------------------------------------
__device__ inline void fft512_wave(float (&xr)[8], float (&xi)[8],
                                   float* sre, float* sim, const int l) {
    dft8(xr, xi);
    twiddle_apply(xr, xi, (NEG2PI / 512.0f) * (float)l);
    const int w0 = l + (l >> 3);
    #pragma unroll
    for (int k = 0; k < 8; ++k) { sre[72 * k + w0] = xr[k]; sim[72 * k + w0] = xi[k]; }
    const int i2 = l & 7;
    const int rbase = 72 * (l >> 3) + i2;
    #pragma unroll
    for (int q = 0; q < 8; ++q) { xr[q] = sre[rbase + 9 * q]; xi[q] = sim[rbase + 9 * q]; }
    dft8(xr, xi);
    twiddle_apply(xr, xi, (NEG2PI / 64.0f) * (float)i2);
    #pragma unroll
    for (int k = 0; k < 8; ++k) { sre[rbase + 9 * k] = xr[k]; sim[rbase + 9 * k] = xi[k]; }
    const int r3 = 9 * l;
    #pragma unroll
    for (int q = 0; q < 8; ++q) { xr[q] = sre[r3 + q]; xi[q] = sim[r3 + q]; }
    dft8(xr, xi);
}

// ---------------------------------------------------------------------------
// Kernel 0: pure streaming T-mean + real-pair pack. One (j, y, 4x-chunk) per
// thread; 16 explicit float4 loads IN FLIGHT before any use (no FFT in this
// kernel -> register allocator can't strangle the batch; VGPR ~80 at
// launch_bounds(256,6) -> ~24 waves/CU). Carries all 128 MiB of input
// traffic. mb[j][y][x] = (meanA, meanB), coalesced 32B stores.
// ---------------------------------------------------------------------------
__global__ __launch_bounds__(256, 6) void kern_mean(const float* __restrict__ in,
                                                    float2* __restrict__ mb) {
    const int g = blockIdx.x * 256 + threadIdx.x;    // 0..524287
    const int c = g & 127;                           // float4 chunk in row
    const int y = (g >> 7) & 511;
    const int j = g >> 16;                           // 0..7
    const float* pa = in + ((size_t)j * 8) * PLANE + (size_t)y * N + 4 * c;
    const float* pb = in + ((size_t)(j + 8) * 8) * PLANE + (size_t)y * N + 4 * c;
    float4 va[8], vb[8];
    #pragma unroll
    for (int tt = 0; tt < 8; ++tt) va[tt] = *(const float4*)(pa + tt * PLANE);
    #pragma unroll
    for (int tt = 0; tt < 8; ++tt) vb[tt] = *(const float4*)(pb + tt * PLANE);
    float4 sa, sb;
    sa.x = ((va[0].x + va[1].x) + (va[2].x + va[3].x)) + ((va[4].x + va[5].x) + (va[6].x + va[7].x));
    sa.y = ((va[0].y + va[1].y) + (va[2].y + va[3].y)) + ((va[4].y + va[5].y) + (va[6].y + va[7].y));
    sa.z = ((va[0].z + va[1].z) + (va[2].z + va[3].z)) + ((va[4].z + va[5].z) + (va[6].z + va[7].z));
    sa.w = ((va[0].w + va[1].w) + (va[2].w + va[3].w)) + ((va[4].w + va[5].w) + (va[6].w + va[7].w));
    sb.x = ((vb[0].x + vb[1].x) + (vb[2].x + vb[3].x)) + ((vb[4].x + vb[5].x) + (vb[6].x + vb[7].x));
    sb.y = ((vb[0].y + vb[1].y) + (vb[2].y + vb[3].y)) + ((vb[4].y + vb[5].y) + (vb[6].y + vb[7].y));
    sb.z = ((vb[0].z + vb[1].z) + (vb[2].z + vb[3].z)) + ((vb[4].z + vb[5].z) + (vb[6].z + vb[7].z));
    sb.w = ((vb[0].w + vb[1].w) + (vb[2].w + vb[3].w)) + ((vb[4].w + vb[5].w) + (vb[6].w + vb[7].w));
    float2* op = mb + ((size_t)j << 18) + ((size_t)y << 9) + 4 * c;
    float4 o0, o1;
    o0.x = sa.x * 0.125f; o0.y = sb.x * 0.125f;     // (re, im) pairs
    o0.z = sa.y * 0.125f; o0.w = sb.y * 0.125f;
    o1.x = sa.z * 0.125f; o1.y = sb.z * 0.125f;
    o1.z = sa.w * 0.125f; o1.w = sb.w * 0.125f;
    *(float4*)(op)     = o0;
    *(float4*)(op + 2) = o1;
}

// ---------------------------------------------------------------------------
// Kernel 1: row FFT. Reads LLC-hot mb directly in FFT lane order (8 coalesced
// 8B loads/lane), per-wave FFT, natural-layout stores to ws[j][y][fx]
// (coalesced despite digit-reversal: per k, lanes cover one 512B segment).
// Block 0 zeroes the bin region. Plane swizzle j = b&7 [R6].
// ---------------------------------------------------------------------------
__global__ __launch_bounds__(256, 4) void kern_rowfft(const float2* __restrict__ mb,
                                                      float2* __restrict__ ws,
                                                      float* __restrict__ bins) {
    __shared__ float sRe[4][576];
    __shared__ float sIm[4][576];
    const int b   = blockIdx.x;
    const int j   = b & 7;
    const int sub = b >> 3;
    const int wv  = threadIdx.x >> 6;
    const int l   = threadIdx.x & 63;
    const int y   = sub * 4 + wv;
    if (b == 0) {
        #pragma unroll
        for (int i = 0; i < 9; ++i) bins[i * 256 + threadIdx.x] = 0.f;
    }
    const float2* rp = mb + ((size_t)j << 18) + ((size_t)y << 9);
    float2 v[8];
    #pragma unroll
    for (int q = 0; q < 8; ++q) v[q] = rp[l + 64 * q];
    float xr[8], xi[8];
    #pragma unroll
    for (int q = 0; q < 8; ++q) { xr[q] = v[q].x; xi[q] = v[q].y; }
    fft512_wave(xr, xi, sRe[wv], sIm[wv], l);
    float2* wp = ws + ((size_t)j << 18) + ((size_t)y << 9);
    #pragma unroll
    for (int k = 0; k < 8; ++k) {
        wp[64 * k + 8 * (l & 7) + (l >> 3)] = make_float2(xr[k], xi[k]);
    }
}

// ---------------------------------------------------------------------------
// Kernel 2: column FFT + radial binning. [R6 verbatim]
// ---------------------------------------------------------------------------
__global__ __launch_bounds__(512, 4) void kern_colfft(const float2* __restrict__ ws,
                                                      float* __restrict__ gseg,
                                                      float* __restrict__ gcnt) {
    __shared__ float sA[8 * 576];
    __shared__ float sB[8 * 576];
    __shared__ float lseg[256];
    __shared__ float lcnt[256];
    const int b   = blockIdx.x;
    const int j   = b & 7;
    const int sub = b >> 3;
    const int fx0 = sub * 8;
    const int t   = threadIdx.x;
    const int w   = t >> 6;
    const int l   = t & 63;
    if (t < 256) { lseg[t] = 0.f; lcnt[t] = 0.f; }
    const float2* base = ws + ((size_t)j << 18) + fx0;
    #pragma unroll
    for (int i = 0; i < 8; ++i) {
        const int y = (w << 6) + (i << 3) + (l >> 3);
        const int f = l & 7;
        float2 v = base[((size_t)y << 9) + f];
        sA[y * 9 + f] = v.x;
        sB[y * 9 + f] = v.y;
    }
    __syncthreads();                 // slab complete, lseg/lcnt zeroed
    float xr[8], xi[8];
    #pragma unroll
    for (int q = 0; q < 8; ++q) {
        const int y = l + (q << 6);
        xr[q] = sA[y * 9 + w];
        xi[q] = sB[y * 9 + w];
    }
    __syncthreads();                 // extracts done; scratch may alias slab
    fft512_wave(xr, xi, sA + w * 576, sB + w * 576, l);
    const int dx  = fx0 + w - 256;
    const int dx2 = dx * dx;
    #pragma unroll
    for (int k = 0; k < 8; ++k) {
        const int fy = 64 * k + 8 * (l & 7) + (l >> 3);
        const int dy = fy - 256;
        const int d2 = dx2 + dy * dy;
        int r = (int)sqrtf((float)d2);
        if ((r + 1) * (r + 1) <= d2) r++;
        else if (r * r > d2) r--;
        if (r >= 1 && r < 256) {
            atomicAdd(&lseg[r], xr[k] * xr[k] + xi[k] * xi[k]);
            if (j == 0) atomicAdd(&lcnt[r], 1.0f);
        }
    }
    __syncthreads();
    if (t < 256) {
        if (lseg[t] != 0.f) atomicAdd(&gseg[j * 256 + t], lseg[t]);
    } else if (j == 0) {
        if (lcnt[t - 256] != 0.f) atomicAdd(&gcnt[t - 256], lcnt[t - 256]);
    }
}

// ---------------------------------------------------------------------------
// Kernel 3: single block — normalized spectra + MSE. [R6 verbatim]
// ---------------------------------------------------------------------------
__global__ __launch_bounds__(256) void kern_loss(const float* __restrict__ gseg,
                                                 const float* __restrict__ gcnt,
                                                 float* __restrict__ out) {
    __shared__ float red[256];
    const int t = threadIdx.x;
    float gen = 0.f, refv = 0.f;
    if (t >= 1) {
        float s = 0.f;
        #pragma unroll
        for (int jj = 0; jj < 8; ++jj) s += gseg[jj * 256 + t];
        float c = gcnt[t];
        gen  = (c > 0.f) ? s / (fmaxf(c, 1.f) * 16.0f) : 0.f;
        refv = exp2f(-1.66666666667f * log2f((float)t));
    }
    red[t] = gen; __syncthreads();
    for (int off = 128; off > 0; off >>= 1) {
        if (t < off) red[t] += red[t + off];
        __syncthreads();
    }
    const float sgen = red[0]; __syncthreads();
    red[t] = refv; __syncthreads();
    for (int off = 128; off > 0; off >>= 1) {
        if (t < off) red[t] += red[t + off];
        __syncthreads();
    }
    const float sref = red[0]; __syncthreads();
    const float gn = gen  / (sgen + 1e-8f);
    const float rn = refv / (sref + 1e-8f);
    red[t] = (gn - rn) * (gn - rn); __syncthreads();
    for (int off = 128; off > 0; off >>= 1) {
        if (t < off) red[t] += red[t + off];
        __syncthreads();
    }
    if (t == 0) out[0] = red[0] / 255.0f;
}

extern "C" void kernel_launch(void* const* d_in, const int* in_sizes, int n_in,
                              void* d_out, int out_size, void* d_ws, size_t ws_size,
                              hipStream_t stream) {
    const float* in = (const float*)d_in[0];
    float2* mb     = (float2*)d_ws;                                  // 16 MiB
    float2* planes = (float2*)((char*)d_ws + (size_t)8 * N * N * sizeof(float2)); // 16 MiB
    float* bins = (float*)((char*)d_ws + (size_t)16 * N * N * sizeof(float2));
    float* gseg = bins;                              // [8][256]
    float* gcnt = bins + 8 * 256;                    // [256]
    kern_mean<<<2048, 256, 0, stream>>>(in, mb);
    kern_rowfft<<<1024, 256, 0, stream>>>(mb, planes, bins);
    kern_colfft<<<512, 512, 0, stream>>>(planes, gseg, gcnt);
    kern_loss<<<1, 256, 0, stream>>>(gseg, gcnt, (float*)d_out);
}